// Round 1
// baseline (275.466 us; speedup 1.0000x reference)
//
#include <hip/hip_runtime.h>

#define NB   4
#define NSEQ 4096
#define DK   64
#define NTOK (NB * NSEQ)

// ---------------------------------------------------------------------------
// Kernel A: Q[b,n] = x.wq, K[b,n] = x.wk, V[b,n,:] = x @ Wv^T + bv
// 256 blocks x 256 threads; 64 tokens per block.
// ---------------------------------------------------------------------------
__global__ __launch_bounds__(256) void qkv_kernel(
    const float* __restrict__ x, const float* __restrict__ Wv,
    const float* __restrict__ bv, const float* __restrict__ wq,
    const float* __restrict__ wk,
    float* __restrict__ Qws, float* __restrict__ Kws, float* __restrict__ Vws)
{
    __shared__ float x_lds[64 * 68];     // padded stride 68: bank-spread, float4-aligned
    __shared__ float wvt[64 * 64];       // wvt[d*64+e] = Wv[e*64+d]
    __shared__ float wqk[64 * 2];
    __shared__ float bvl[64];

    const int t = threadIdx.x;
    const int tok0 = blockIdx.x * 64;

    // stage x tile (16 KB contiguous) -> padded LDS
    #pragma unroll
    for (int r = 0; r < 4; ++r) {
        int f = t + 256 * r;             // float4 index 0..1023
        int row = f >> 4, c4 = f & 15;
        float4 v = ((const float4*)(x + (size_t)(tok0 + row) * DK))[c4];
        *(float4*)&x_lds[row * 68 + c4 * 4] = v;
    }
    // stage Wv transposed
    #pragma unroll
    for (int r = 0; r < 4; ++r) {
        int f = t + 256 * r;
        int e = f >> 4, c4 = f & 15;
        float4 v = ((const float4*)(Wv + e * DK))[c4];
        wvt[(c4 * 4 + 0) * 64 + e] = v.x;
        wvt[(c4 * 4 + 1) * 64 + e] = v.y;
        wvt[(c4 * 4 + 2) * 64 + e] = v.z;
        wvt[(c4 * 4 + 3) * 64 + e] = v.w;
    }
    if (t < 64) { wqk[t * 2] = wq[t]; wqk[t * 2 + 1] = wk[t]; bvl[t] = bv[t]; }
    __syncthreads();

    // V: thread (tok = t>>2, q = t&3) computes e in [q*16, q*16+16)
    const int tok = t >> 2, q = t & 3;
    const int e0 = q * 16;
    float acc[16];
    #pragma unroll
    for (int ee = 0; ee < 16; ++ee) acc[ee] = bvl[e0 + ee];

    for (int d = 0; d < DK; d += 4) {
        float4 x4 = *(const float4*)&x_lds[tok * 68 + d];
        const float xs[4] = {x4.x, x4.y, x4.z, x4.w};
        #pragma unroll
        for (int dd = 0; dd < 4; ++dd) {
            float xv = xs[dd];
            const float4* wrow = (const float4*)&wvt[(d + dd) * 64 + e0];
            #pragma unroll
            for (int c = 0; c < 4; ++c) {
                float4 w4 = wrow[c];
                acc[c * 4 + 0] += xv * w4.x;
                acc[c * 4 + 1] += xv * w4.y;
                acc[c * 4 + 2] += xv * w4.z;
                acc[c * 4 + 3] += xv * w4.w;
            }
        }
    }
    float* vdst = Vws + (size_t)(tok0 + tok) * DK + e0;
    #pragma unroll
    for (int c = 0; c < 4; ++c) {
        float4 o = make_float4(acc[c*4+0], acc[c*4+1], acc[c*4+2], acc[c*4+3]);
        ((float4*)vdst)[c] = o;
    }

    // Q/K: first wave, one token per lane
    if (t < 64) {
        float qv = 0.f, kv = 0.f;
        for (int d = 0; d < DK; ++d) {
            float xv = x_lds[t * 68 + d];
            qv += xv * wqk[d * 2];
            kv += xv * wqk[d * 2 + 1];
        }
        Qws[tok0 + t] = qv;
        Kws[tok0 + t] = kv;
    }
}

// ---------------------------------------------------------------------------
// Kernel B: attention + residual + layernorm.
// 256 blocks (b in [0,4), 64-row i-tile) x 256 threads.
// Register tile: 16x16 thread grid, 4i x 4d per thread.
// j streamed in 64-wide tiles; w-tile in LDS; V tile reg-prefetched -> LDS.
// ---------------------------------------------------------------------------
__global__ __launch_bounds__(256) void attn_kernel(
    const float* __restrict__ x,
    const float* __restrict__ Qws, const float* __restrict__ Kws,
    const float* __restrict__ Vws,
    const float* __restrict__ gamma, const float* __restrict__ beta,
    float* __restrict__ out)
{
    __shared__ float k_all[NSEQ];        // all K for this batch (16 KB)
    __shared__ float w_lds[64 * 64];     // w[j][i] layout
    __shared__ float v_lds[64 * 64];     // V tile, row-major [j][d]
    __shared__ float denom_lds[4 * 64];

    const int t  = threadIdx.x;
    const int b  = blockIdx.x >> 6;
    const int i0 = (blockIdx.x & 63) << 6;

    // stage all K[b,:]
    #pragma unroll
    for (int r = 0; r < 4; ++r) {
        int f = t + 256 * r;
        ((float4*)k_all)[f] = ((const float4*)(Kws + b * NSEQ))[f];
    }

    const int i_w = t & 63, jg = t >> 6;        // w-phase mapping
    const float Qi = Qws[b * NSEQ + i0 + i_w];

    const float* Vb = Vws + (size_t)b * NSEQ * DK;
    float4 vreg[4];
    #pragma unroll
    for (int r = 0; r < 4; ++r) vreg[r] = ((const float4*)Vb)[t + 256 * r];  // tile 0

    const int ti = t >> 4, td = t & 15;          // fma-phase mapping
    float4 acc[4];
    #pragma unroll
    for (int ii = 0; ii < 4; ++ii) acc[ii] = make_float4(0.f, 0.f, 0.f, 0.f);
    float denom = 0.f;

    __syncthreads();  // k_all ready

    for (int jt = 0; jt < 64; ++jt) {
        // ---- w-phase: compute 64x64 score tile into LDS (16 pairs/thread)
        const int jbase = jt * 64;
        #pragma unroll
        for (int jj = 0; jj < 16; ++jj) {
            int j = jg * 16 + jj;
            float kv = k_all[jbase + j];
            float d  = Qi - kv;
            float g  = __expf(-d * d);           // A = exp(-(Qi-Kj)^2), in (0,1]
            float wv = __expf(0.125f * g);       // exp(A/sqrt(dk)); stable, no max needed
            denom += wv;
            w_lds[j * 64 + i_w] = wv;
        }
        // ---- stage prefetched V tile jt into LDS
        #pragma unroll
        for (int r = 0; r < 4; ++r)
            ((float4*)v_lds)[t + 256 * r] = vreg[r];
        __syncthreads();

        // ---- prefetch next V tile into registers (hidden under fma phase)
        if (jt < 63) {
            const float4* src = (const float4*)Vb + (size_t)(jt + 1) * 1024;
            #pragma unroll
            for (int r = 0; r < 4; ++r) vreg[r] = src[t + 256 * r];
        }

        // ---- fma phase: acc[i..i+4][d..d+4] += w[j][i..] * V[j][d..]
        const float* wrow = w_lds + (ti << 2);
        const float* vrow = v_lds + (td << 2);
        #pragma unroll 4
        for (int j = 0; j < 64; ++j) {
            float4 w4 = *(const float4*)(wrow + j * 64);
            float4 v4 = *(const float4*)(vrow + j * 64);
            acc[0].x += w4.x * v4.x; acc[0].y += w4.x * v4.y;
            acc[0].z += w4.x * v4.z; acc[0].w += w4.x * v4.w;
            acc[1].x += w4.y * v4.x; acc[1].y += w4.y * v4.y;
            acc[1].z += w4.y * v4.z; acc[1].w += w4.y * v4.w;
            acc[2].x += w4.z * v4.x; acc[2].y += w4.z * v4.y;
            acc[2].z += w4.z * v4.z; acc[2].w += w4.z * v4.w;
            acc[3].x += w4.w * v4.x; acc[3].y += w4.w * v4.y;
            acc[3].z += w4.w * v4.z; acc[3].w += w4.w * v4.w;
        }
        __syncthreads();
    }

    // ---- epilogue: softmax divide, +x residual, layernorm, store
    denom_lds[jg * 64 + i_w] = denom;
    __syncthreads();

    const int d0 = td * 4;
    const float4 g4 = *(const float4*)(gamma + d0);
    const float4 b4 = *(const float4*)(beta + d0);

    #pragma unroll
    for (int ii = 0; ii < 4; ++ii) {
        int i_loc = (ti << 2) + ii;
        float dsum = denom_lds[i_loc] + denom_lds[64 + i_loc] +
                     denom_lds[128 + i_loc] + denom_lds[192 + i_loc];
        float inv = 1.f / dsum;
        size_t row = (size_t)(b * NSEQ + i0 + i_loc);
        float4 x4 = *(const float4*)(x + row * DK + d0);
        float4 h;
        h.x = acc[ii].x * inv + x4.x;
        h.y = acc[ii].y * inv + x4.y;
        h.z = acc[ii].z * inv + x4.z;
        h.w = acc[ii].w * inv + x4.w;

        float s  = h.x + h.y + h.z + h.w;
        float ss = h.x * h.x + h.y * h.y + h.z * h.z + h.w * h.w;
        // reduce across the 16 lanes sharing ti (lanes differ only in td = t&15)
        #pragma unroll
        for (int m = 1; m < 16; m <<= 1) {
            s  += __shfl_xor(s, m);
            ss += __shfl_xor(ss, m);
        }
        float mu   = s * (1.f / 64.f);
        float var  = ss * (1.f / 64.f) - mu * mu;
        float rstd = rsqrtf(var + 1e-5f);

        float4 o;
        o.x = (h.x - mu) * rstd * g4.x + b4.x;
        o.y = (h.y - mu) * rstd * g4.y + b4.y;
        o.z = (h.z - mu) * rstd * g4.z + b4.z;
        o.w = (h.w - mu) * rstd * g4.w + b4.w;
        *(float4*)(out + row * DK + d0) = o;
    }
}

// ---------------------------------------------------------------------------
extern "C" void kernel_launch(void* const* d_in, const int* in_sizes, int n_in,
                              void* d_out, int out_size, void* d_ws, size_t ws_size,
                              hipStream_t stream)
{
    const float* x     = (const float*)d_in[0];
    const float* Wv    = (const float*)d_in[1];
    const float* bv    = (const float*)d_in[2];
    const float* wq    = (const float*)d_in[3];
    const float* wk    = (const float*)d_in[4];
    const float* gamma = (const float*)d_in[5];
    const float* beta  = (const float*)d_in[6];
    float* out = (float*)d_out;

    // workspace layout: Q[16384] | K[16384] | V[16384*64]  (~4.13 MB)
    float* Qws = (float*)d_ws;
    float* Kws = Qws + NTOK;
    float* Vws = Kws + NTOK;

    qkv_kernel<<<dim3(NTOK / 64), dim3(256), 0, stream>>>(x, Wv, bv, wq, wk, Qws, Kws, Vws);
    attn_kernel<<<dim3(NB * (NSEQ / 64)), dim3(256), 0, stream>>>(x, Qws, Kws, Vws, gamma, beta, out);
}

// Round 2
// 133.794 us; speedup vs baseline: 2.0589x; 2.0589x over previous
//
#include <hip/hip_runtime.h>

#define NB   4
#define NSEQ 4096
#define DK   64
#define NTOK (NB * NSEQ)

#define QK_SCALE 1.2011224087864498f   // sqrt(log2(e))

typedef __attribute__((ext_vector_type(8))) short short8;
typedef __attribute__((ext_vector_type(4))) float f32x4;

__device__ __forceinline__ float fast_exp2(float x) {
#if __has_builtin(__builtin_amdgcn_exp2f)
    return __builtin_amdgcn_exp2f(x);
#else
    return exp2f(x);
#endif
}

__device__ __forceinline__ unsigned short bf16_rne(float f) {
    unsigned u = __float_as_uint(f);
    u += 0x7fffu + ((u >> 16) & 1u);
    return (unsigned short)(u >> 16);
}

__device__ __forceinline__ short8 u4_to_s8(uint4 u) {
    union { uint4 u; short8 s; } c; c.u = u; return c.s;
}

// ---------------------------------------------------------------------------
// Kernel A: Qs[b,n] = (x.wq)*QK_SCALE, Ks likewise, Vt[b][d][n] = bf16(x@Wv^T+bv)
// 256 blocks x 256 threads; 64 tokens per block.
// ---------------------------------------------------------------------------
__global__ __launch_bounds__(256) void qkv_kernel(
    const float* __restrict__ x, const float* __restrict__ Wv,
    const float* __restrict__ bv, const float* __restrict__ wq,
    const float* __restrict__ wk,
    float* __restrict__ Qs, float* __restrict__ Ks, unsigned short* __restrict__ Vt)
{
    __shared__ float x_lds[64 * 68];
    __shared__ float wvt[64 * 64];        // wvt[d*64+e] = Wv[e*64+d]
    __shared__ float wqk[128];
    __shared__ float bvl[64];
    __shared__ unsigned short vt_lds[64 * 72];   // [e][tok], stride 72 (144 B, 16B-aligned)

    const int t = threadIdx.x;
    const int tok0 = blockIdx.x * 64;

    #pragma unroll
    for (int r = 0; r < 4; ++r) {
        int f = t + 256 * r;
        int row = f >> 4, c4 = f & 15;
        float4 v = ((const float4*)(x + (size_t)(tok0 + row) * DK))[c4];
        *(float4*)&x_lds[row * 68 + c4 * 4] = v;
    }
    #pragma unroll
    for (int r = 0; r < 4; ++r) {
        int f = t + 256 * r;
        int e = f >> 4, c4 = f & 15;
        float4 v = ((const float4*)(Wv + e * DK))[c4];
        wvt[(c4 * 4 + 0) * 64 + e] = v.x;
        wvt[(c4 * 4 + 1) * 64 + e] = v.y;
        wvt[(c4 * 4 + 2) * 64 + e] = v.z;
        wvt[(c4 * 4 + 3) * 64 + e] = v.w;
    }
    if (t < 64) { wqk[t * 2] = wq[t]; wqk[t * 2 + 1] = wk[t]; bvl[t] = bv[t]; }
    __syncthreads();

    const int tok = t >> 2, q = t & 3;
    const int e0 = q * 16;
    float acc[16];
    #pragma unroll
    for (int ee = 0; ee < 16; ++ee) acc[ee] = bvl[e0 + ee];

    for (int d = 0; d < DK; d += 4) {
        float4 x4 = *(const float4*)&x_lds[tok * 68 + d];
        const float xs[4] = {x4.x, x4.y, x4.z, x4.w};
        #pragma unroll
        for (int dd = 0; dd < 4; ++dd) {
            float xv = xs[dd];
            const float4* wrow = (const float4*)&wvt[(d + dd) * 64 + e0];
            #pragma unroll
            for (int c = 0; c < 4; ++c) {
                float4 w4 = wrow[c];
                acc[c * 4 + 0] += xv * w4.x;
                acc[c * 4 + 1] += xv * w4.y;
                acc[c * 4 + 2] += xv * w4.z;
                acc[c * 4 + 3] += xv * w4.w;
            }
        }
    }
    // transposed bf16 V tile into LDS
    #pragma unroll
    for (int k = 0; k < 16; ++k)
        vt_lds[(e0 + k) * 72 + tok] = bf16_rne(acc[k]);

    // Q/K (pre-scaled for exp2-based score math)
    if (t < 64) {
        float qv = 0.f, kv = 0.f;
        for (int d = 0; d < DK; ++d) {
            float xv = x_lds[t * 68 + d];
            qv += xv * wqk[d * 2];
            kv += xv * wqk[d * 2 + 1];
        }
        Qs[tok0 + t] = qv * QK_SCALE;
        Ks[tok0 + t] = kv * QK_SCALE;
    }
    __syncthreads();

    // coalesced global write of Vt rows: 64 d-rows x 128 B
    const int bb = tok0 >> 12, n0 = tok0 & 4095;
    #pragma unroll
    for (int r = 0; r < 2; ++r) {
        int f = t + 256 * r;
        int d = f >> 3, c = f & 7;
        uint4 v = *(const uint4*)((const char*)vt_lds + d * 144 + c * 16);
        *(uint4*)(Vt + (size_t)(bb * 64 + d) * 4096 + n0 + c * 8) = v;
    }
}

// ---------------------------------------------------------------------------
// Kernel B: MFMA attention + residual + layernorm.
// 256 blocks (b, 64-row i-tile) x 4 waves.
// Wave w: rows rgrp*32..+32 (2 MFMA row-tiles), K-half (w&1).
// Scores built in-register in A-fragment layout; V from LDS (B-frag b128 reads).
// In-block K-half combine, fused epilogue.
// ---------------------------------------------------------------------------
__global__ __launch_bounds__(256, 1) void attn_kernel(
    const float* __restrict__ x,
    const float* __restrict__ Qsg, const float* __restrict__ Ksg,
    const unsigned short* __restrict__ Vt,
    const float* __restrict__ gamma, const float* __restrict__ beta,
    float* __restrict__ out)
{
    __shared__ float k_lds[4096];                     // all scaled K of batch (16 KB)
    __shared__ unsigned short vt_lds[2 * 64 * 136];   // 2 K-half bufs, 64 d x (128+8 pad) j
    __shared__ float dred[64];

    const int t    = threadIdx.x;
    const int b    = blockIdx.x >> 6;
    const int i0   = (blockIdx.x & 63) << 6;
    const int w    = t >> 6;
    const int lane = t & 63;
    const int rit  = lane & 15;       // MFMA row (A) / col-in-tile (B,C/D)
    const int q    = lane >> 4;       // quad
    const int half = w & 1;           // K-half this wave processes
    const int rgrp = w >> 1;          // row group (32 rows)

    // stage K
    {
        const uint4* src = (const uint4*)(Ksg + b * 4096);
        #pragma unroll
        for (int r = 0; r < 4; ++r) ((uint4*)k_lds)[t + 256 * r] = src[t + 256 * r];
    }

    const float Qs0 = Qsg[b * 4096 + i0 + rgrp * 32 + rit];
    const float Qs1 = Qsg[b * 4096 + i0 + rgrp * 32 + 16 + rit];
    const unsigned short* Vtb = Vt + (size_t)b * 64 * 4096;

    // register prefetch of chunk 0 (both half-buffers)
    uint4 pf[8];
    #pragma unroll
    for (int r = 0; r < 8; ++r) {
        int f = t + 256 * r; int buf = f >> 10; int rem = f & 1023;
        int d = rem >> 4, c = rem & 15;
        pf[r] = *(const uint4*)(Vtb + (size_t)d * 4096 + buf * 2048 + c * 8);
    }

    f32x4 acc[2][4] = {};
    float denom0 = 0.f, denom1 = 0.f;

    const char* vtbase = (const char*)vt_lds + half * 17408 + rit * 272;
    const int kbase0 = half * 2048;

    for (int chunk = 0; chunk < 16; ++chunk) {
        __syncthreads();
        #pragma unroll
        for (int r = 0; r < 8; ++r) {
            int f = t + 256 * r; int buf = f >> 10; int rem = f & 1023;
            int d = rem >> 4, c = rem & 15;
            *(uint4*)((char*)vt_lds + buf * 17408 + d * 272 + c * 16) = pf[r];
        }
        __syncthreads();
        if (chunk < 15) {
            #pragma unroll
            for (int r = 0; r < 8; ++r) {
                int f = t + 256 * r; int buf = f >> 10; int rem = f & 1023;
                int d = rem >> 4, c = rem & 15;
                pf[r] = *(const uint4*)(Vtb + (size_t)d * 4096 + buf * 2048 + (chunk + 1) * 128 + c * 8);
            }
        }
        #pragma unroll
        for (int ks = 0; ks < 4; ++ks) {
            const float* kp = &k_lds[kbase0 + chunk * 128 + ks * 32 + q * 8];
            float4 ka = *(const float4*)kp;
            float4 kb = *(const float4*)(kp + 4);
            float kv[8] = {ka.x, ka.y, ka.z, ka.w, kb.x, kb.y, kb.z, kb.w};

            float wv0[8], wv1[8];
            #pragma unroll
            for (int jj = 0; jj < 8; ++jj) {
                float d0 = Qs0 - kv[jj];
                float g0 = fast_exp2(-d0 * d0);          // = exp(-(Q-K)^2)
                float p0 = __builtin_fmaf(g0, 3.2552083e-4f, 7.8125e-3f);
                p0 = __builtin_fmaf(g0, p0, 0.125f);
                wv0[jj] = __builtin_fmaf(g0, p0, 1.0f);  // = exp(g/8), err<1e-5
                denom0 += wv0[jj];
                float d1 = Qs1 - kv[jj];
                float g1 = fast_exp2(-d1 * d1);
                float p1 = __builtin_fmaf(g1, 3.2552083e-4f, 7.8125e-3f);
                p1 = __builtin_fmaf(g1, p1, 0.125f);
                wv1[jj] = __builtin_fmaf(g1, p1, 1.0f);
                denom1 += wv1[jj];
            }
            // pack to bf16 (truncation; bias cancels in the softmax ratio)
            uint4 au0, au1;
            au0.x = __builtin_amdgcn_perm(__float_as_uint(wv0[1]), __float_as_uint(wv0[0]), 0x07060302u);
            au0.y = __builtin_amdgcn_perm(__float_as_uint(wv0[3]), __float_as_uint(wv0[2]), 0x07060302u);
            au0.z = __builtin_amdgcn_perm(__float_as_uint(wv0[5]), __float_as_uint(wv0[4]), 0x07060302u);
            au0.w = __builtin_amdgcn_perm(__float_as_uint(wv0[7]), __float_as_uint(wv0[6]), 0x07060302u);
            au1.x = __builtin_amdgcn_perm(__float_as_uint(wv1[1]), __float_as_uint(wv1[0]), 0x07060302u);
            au1.y = __builtin_amdgcn_perm(__float_as_uint(wv1[3]), __float_as_uint(wv1[2]), 0x07060302u);
            au1.z = __builtin_amdgcn_perm(__float_as_uint(wv1[5]), __float_as_uint(wv1[4]), 0x07060302u);
            au1.w = __builtin_amdgcn_perm(__float_as_uint(wv1[7]), __float_as_uint(wv1[6]), 0x07060302u);
            short8 a0 = u4_to_s8(au0);
            short8 a1 = u4_to_s8(au1);

            const char* vks = vtbase + ks * 64 + q * 16;
            #pragma unroll
            for (int ct = 0; ct < 4; ++ct) {
                short8 b8 = u4_to_s8(*(const uint4*)(vks + ct * 16 * 272));
                acc[0][ct] = __builtin_amdgcn_mfma_f32_16x16x32_bf16(a0, b8, acc[0][ct], 0, 0, 0);
                acc[1][ct] = __builtin_amdgcn_mfma_f32_16x16x32_bf16(a1, b8, acc[1][ct], 0, 0, 0);
            }
        }
    }

    // full-row denominators within this K-half (reduce across quads)
    denom0 += __shfl_xor(denom0, 16); denom0 += __shfl_xor(denom0, 32);
    denom1 += __shfl_xor(denom1, 16); denom1 += __shfl_xor(denom1, 32);

    __syncthreads();
    float* red = (float*)vt_lds;   // reuse: 64 rows x 64 cols fp32 partials (16 KB)
    if (half == 1) {
        #pragma unroll
        for (int rt = 0; rt < 2; ++rt)
            #pragma unroll
            for (int ct = 0; ct < 4; ++ct)
                #pragma unroll
                for (int rg = 0; rg < 4; ++rg)
                    red[(rgrp * 32 + rt * 16 + q * 4 + rg) * 64 + ct * 16 + rit] = acc[rt][ct][rg];
        if (q == 0) dred[rgrp * 32 + rit] = denom0;
        if (q == 1) dred[rgrp * 32 + 16 + rit] = denom1;
    }
    __syncthreads();
    if (half == 0) {
        denom0 += dred[rgrp * 32 + rit];
        denom1 += dred[rgrp * 32 + 16 + rit];
        const int col = rit;
        float ga[4], be[4];
        #pragma unroll
        for (int ct = 0; ct < 4; ++ct) { ga[ct] = gamma[ct * 16 + col]; be[ct] = beta[ct * 16 + col]; }
        #pragma unroll
        for (int rt = 0; rt < 2; ++rt) {
            float dn = rt ? denom1 : denom0;
            #pragma unroll
            for (int rg = 0; rg < 4; ++rg) {
                int rloc = q * 4 + rg;
                float dr = __shfl(dn, rloc, 16);
                float inv = 1.0f / dr;
                int row_loc = rgrp * 32 + rt * 16 + rloc;
                size_t rowg = (size_t)(b * 4096 + i0 + row_loc);
                const float* xr = x + rowg * 64;
                float h[4], s = 0.f, ss = 0.f;
                #pragma unroll
                for (int ct = 0; ct < 4; ++ct) {
                    float num = acc[rt][ct][rg] + red[row_loc * 64 + ct * 16 + col];
                    h[ct] = num * inv + xr[ct * 16 + col];
                    s += h[ct]; ss += h[ct] * h[ct];
                }
                #pragma unroll
                for (int m = 1; m < 16; m <<= 1) { s += __shfl_xor(s, m); ss += __shfl_xor(ss, m); }
                float mu   = s * 0.015625f;
                float var  = ss * 0.015625f - mu * mu;
                float rstd = rsqrtf(var + 1e-5f);
                float* orow = out + rowg * 64;
                #pragma unroll
                for (int ct = 0; ct < 4; ++ct)
                    orow[ct * 16 + col] = (h[ct] - mu) * rstd * ga[ct] + be[ct];
            }
        }
    }
}

// ---------------------------------------------------------------------------
extern "C" void kernel_launch(void* const* d_in, const int* in_sizes, int n_in,
                              void* d_out, int out_size, void* d_ws, size_t ws_size,
                              hipStream_t stream)
{
    const float* x     = (const float*)d_in[0];
    const float* Wv    = (const float*)d_in[1];
    const float* bv    = (const float*)d_in[2];
    const float* wq    = (const float*)d_in[3];
    const float* wk    = (const float*)d_in[4];
    const float* gamma = (const float*)d_in[5];
    const float* beta  = (const float*)d_in[6];
    float* out = (float*)d_out;

    // workspace: Qs[16384] f32 | Ks[16384] f32 | Vt[4*64*4096] bf16  (~2.23 MB)
    float* Qs = (float*)d_ws;
    float* Ks = Qs + NTOK;
    unsigned short* Vt = (unsigned short*)(Ks + NTOK);

    qkv_kernel<<<dim3(NTOK / 64), dim3(256), 0, stream>>>(x, Wv, bv, wq, wk, Qs, Ks, Vt);
    attn_kernel<<<dim3(NB * (NSEQ / 64)), dim3(256), 0, stream>>>(x, Qs, Ks, Vt, gamma, beta, out);
}

// Round 3
// 104.672 us; speedup vs baseline: 2.6317x; 1.2782x over previous
//
#include <hip/hip_runtime.h>

#define NB   4
#define NSEQ 4096
#define DK   64
#define NTOK (NB * NSEQ)

#define QK_SCALE 1.2011224087864498f   // sqrt(log2(e))

typedef __attribute__((ext_vector_type(8))) short short8;
typedef __attribute__((ext_vector_type(4))) float f32x4;

__device__ __forceinline__ float fast_exp2(float x) {
#if __has_builtin(__builtin_amdgcn_exp2f)
    return __builtin_amdgcn_exp2f(x);
#else
    return exp2f(x);
#endif
}

__device__ __forceinline__ unsigned short bf16_rne(float f) {
    unsigned u = __float_as_uint(f);
    u += 0x7fffu + ((u >> 16) & 1u);
    return (unsigned short)(u >> 16);
}

__device__ __forceinline__ short8 u4_to_s8(uint4 u) {
    union { uint4 u; short8 s; } c; c.u = u; return c.s;
}

// ---------------------------------------------------------------------------
// Kernel A: Qs/Ks = (x.wq/wk)*QK_SCALE, Vt[b][d][n] = bf16(x@Wv^T+bv)
// 256 blocks x 512 threads (2 waves/SIMD); 64 tokens per block.
// ---------------------------------------------------------------------------
__global__ __launch_bounds__(512) void qkv_kernel(
    const float* __restrict__ x, const float* __restrict__ Wv,
    const float* __restrict__ bv, const float* __restrict__ wq,
    const float* __restrict__ wk,
    float* __restrict__ Qs, float* __restrict__ Ks, unsigned short* __restrict__ Vt)
{
    __shared__ float x_lds[64 * 68];
    __shared__ float wvt[64 * 68];        // wvt[d*68+e] = Wv[e*64+d], stride 68
    __shared__ float wqk[128];
    __shared__ float bvl[64];
    __shared__ unsigned short vt_lds[64 * 72];   // [e][tok]

    const int t = threadIdx.x;
    const int tok0 = blockIdx.x * 64;

    #pragma unroll
    for (int r = 0; r < 2; ++r) {
        int f = t + 512 * r;
        int row = f >> 4, c4 = f & 15;
        float4 v = ((const float4*)(x + (size_t)(tok0 + row) * DK))[c4];
        *(float4*)&x_lds[row * 68 + c4 * 4] = v;
    }
    #pragma unroll
    for (int r = 0; r < 2; ++r) {
        int f = t + 512 * r;
        int e = f >> 4, c4 = f & 15;
        float4 v = ((const float4*)(Wv + e * DK))[c4];
        wvt[(c4 * 4 + 0) * 68 + e] = v.x;
        wvt[(c4 * 4 + 1) * 68 + e] = v.y;
        wvt[(c4 * 4 + 2) * 68 + e] = v.z;
        wvt[(c4 * 4 + 3) * 68 + e] = v.w;
    }
    if (t < 64) { wqk[t * 2] = wq[t]; wqk[t * 2 + 1] = wk[t]; bvl[t] = bv[t]; }
    __syncthreads();

    // V: thread (tok = t>>3, oc = t&7) computes e in [oc*8, oc*8+8)
    const int tok = t >> 3, oc = t & 7;
    const int e0 = oc * 8;
    float acc[8];
    #pragma unroll
    for (int ee = 0; ee < 8; ++ee) acc[ee] = bvl[e0 + ee];

    for (int d = 0; d < DK; d += 4) {
        float4 x4 = *(const float4*)&x_lds[tok * 68 + d];
        const float xs[4] = {x4.x, x4.y, x4.z, x4.w};
        #pragma unroll
        for (int dd = 0; dd < 4; ++dd) {
            float xv = xs[dd];
            const float4* wrow = (const float4*)&wvt[(d + dd) * 68 + e0];
            float4 wa = wrow[0], wb = wrow[1];
            acc[0] += xv * wa.x; acc[1] += xv * wa.y;
            acc[2] += xv * wa.z; acc[3] += xv * wa.w;
            acc[4] += xv * wb.x; acc[5] += xv * wb.y;
            acc[6] += xv * wb.z; acc[7] += xv * wb.w;
        }
    }
    #pragma unroll
    for (int k = 0; k < 8; ++k)
        vt_lds[(e0 + k) * 72 + tok] = bf16_rne(acc[k]);

    // Q (wave 0) / K (wave 1), pre-scaled for exp2-based score math
    if (t < 128) {
        const int tk = t & 63;
        const int sel = (t >= 64);
        float a = 0.f;
        for (int d = 0; d < DK; ++d)
            a += x_lds[tk * 68 + d] * wqk[d * 2 + sel];
        (sel ? Ks : Qs)[tok0 + tk] = a * QK_SCALE;
    }
    __syncthreads();

    // coalesced global write of Vt rows: 64 d-rows x 128 B
    const int bb = tok0 >> 12, n0 = tok0 & 4095;
    {
        int d = t >> 3, c = t & 7;
        uint4 v = *(const uint4*)((const char*)vt_lds + d * 144 + c * 16);
        *(uint4*)(Vt + (size_t)(bb * 64 + d) * 4096 + n0 + c * 8) = v;
    }
}

// ---------------------------------------------------------------------------
// Kernel B: MFMA attention + residual + layernorm.
// 256 blocks (b, 64-row i-tile) x 1024 threads (16 waves = 4/SIMD).
// Wave w: rgrp = w>>3 (32 rows = 2 MFMA row tiles), je = w&7 (512-j slice).
// B-fragments loaded DIRECTLY from global Vt[d][n] (no LDS staging, no
// main-loop barriers). Denominator via MFMA with ones-B. 8-way j-split
// combined through padded LDS slots, epilogue redistributed block-wide.
// ---------------------------------------------------------------------------
extern __shared__ float smem[];

__global__ __launch_bounds__(1024, 4) void attn_kernel(
    const float* __restrict__ x,
    const float* __restrict__ Qsg, const float* __restrict__ Ksg,
    const unsigned short* __restrict__ Vt,
    const float* __restrict__ gamma, const float* __restrict__ beta,
    float* __restrict__ out)
{
    float* k_lds = smem;                       // 4096 floats
    float* red   = smem + 4096;                // 8 slots x 64 rows x stride 68
    float* dred  = smem + 4096 + 8 * 64 * 68;  // 8 x 64

    const int t    = threadIdx.x;
    const int b    = blockIdx.x >> 6;
    const int i0   = (blockIdx.x & 63) << 6;
    const int w    = t >> 6;
    const int lane = t & 63;
    const int rit  = lane & 15;
    const int q    = lane >> 4;
    const int rgrp = w >> 3;          // 0..1: 32-row group
    const int je   = w & 7;           // 0..7: 512-wide j slice

    ((float4*)k_lds)[t] = ((const float4*)(Ksg + (size_t)b * 4096))[t];

    const float Qs0 = Qsg[b * 4096 + i0 + rgrp * 32 + rit];
    const float Qs1 = Qsg[b * 4096 + i0 + rgrp * 32 + 16 + rit];
    const unsigned short* Vtb = Vt + (size_t)b * 64 * 4096 + (size_t)rit * 4096;

    f32x4 acc[2][4] = {};
    f32x4 accd[2] = {};
    const short onebf = (short)0x3F80;
    const short8 vones = {onebf, onebf, onebf, onebf, onebf, onebf, onebf, onebf};

    __syncthreads();   // k_lds ready

    const int jw = je * 512;
    for (int s = 0; s < 16; ++s) {
        const int j0 = jw + s * 32;
        // ---- B fragments straight from global (L2-resident Vt)
        const unsigned short* vb = Vtb + j0 + q * 8;
        uint4 bu0 = *(const uint4*)(vb);
        uint4 bu1 = *(const uint4*)(vb + 16 * 4096);
        uint4 bu2 = *(const uint4*)(vb + 32 * 4096);
        uint4 bu3 = *(const uint4*)(vb + 48 * 4096);

        // ---- scores (A fragments) for 2 row tiles
        const float* kp = &k_lds[j0 + q * 8];
        float4 ka = *(const float4*)kp;
        float4 kb = *(const float4*)(kp + 4);
        float kv[8] = {ka.x, ka.y, ka.z, ka.w, kb.x, kb.y, kb.z, kb.w};
        float w0[8], w1[8];
        #pragma unroll
        for (int jj = 0; jj < 8; ++jj) {
            float d0 = Qs0 - kv[jj];
            float g0 = fast_exp2(-d0 * d0);
            float p0 = __builtin_fmaf(g0, 3.2552083e-4f, 7.8125e-3f);
            p0 = __builtin_fmaf(g0, p0, 0.125f);
            w0[jj] = __builtin_fmaf(g0, p0, 1.0f);     // exp(exp(-(Q-K)^2)/8)
            float d1 = Qs1 - kv[jj];
            float g1 = fast_exp2(-d1 * d1);
            float p1 = __builtin_fmaf(g1, 3.2552083e-4f, 7.8125e-3f);
            p1 = __builtin_fmaf(g1, p1, 0.125f);
            w1[jj] = __builtin_fmaf(g1, p1, 1.0f);
        }
        uint4 au0, au1;
        au0.x = __builtin_amdgcn_perm(__float_as_uint(w0[1]), __float_as_uint(w0[0]), 0x07060302u);
        au0.y = __builtin_amdgcn_perm(__float_as_uint(w0[3]), __float_as_uint(w0[2]), 0x07060302u);
        au0.z = __builtin_amdgcn_perm(__float_as_uint(w0[5]), __float_as_uint(w0[4]), 0x07060302u);
        au0.w = __builtin_amdgcn_perm(__float_as_uint(w0[7]), __float_as_uint(w0[6]), 0x07060302u);
        au1.x = __builtin_amdgcn_perm(__float_as_uint(w1[1]), __float_as_uint(w1[0]), 0x07060302u);
        au1.y = __builtin_amdgcn_perm(__float_as_uint(w1[3]), __float_as_uint(w1[2]), 0x07060302u);
        au1.z = __builtin_amdgcn_perm(__float_as_uint(w1[5]), __float_as_uint(w1[4]), 0x07060302u);
        au1.w = __builtin_amdgcn_perm(__float_as_uint(w1[7]), __float_as_uint(w1[6]), 0x07060302u);
        short8 a0 = u4_to_s8(au0);
        short8 a1 = u4_to_s8(au1);

        short8 b0 = u4_to_s8(bu0), b1 = u4_to_s8(bu1);
        short8 b2 = u4_to_s8(bu2), b3 = u4_to_s8(bu3);
        acc[0][0] = __builtin_amdgcn_mfma_f32_16x16x32_bf16(a0, b0, acc[0][0], 0, 0, 0);
        acc[0][1] = __builtin_amdgcn_mfma_f32_16x16x32_bf16(a0, b1, acc[0][1], 0, 0, 0);
        acc[0][2] = __builtin_amdgcn_mfma_f32_16x16x32_bf16(a0, b2, acc[0][2], 0, 0, 0);
        acc[0][3] = __builtin_amdgcn_mfma_f32_16x16x32_bf16(a0, b3, acc[0][3], 0, 0, 0);
        acc[1][0] = __builtin_amdgcn_mfma_f32_16x16x32_bf16(a1, b0, acc[1][0], 0, 0, 0);
        acc[1][1] = __builtin_amdgcn_mfma_f32_16x16x32_bf16(a1, b1, acc[1][1], 0, 0, 0);
        acc[1][2] = __builtin_amdgcn_mfma_f32_16x16x32_bf16(a1, b2, acc[1][2], 0, 0, 0);
        acc[1][3] = __builtin_amdgcn_mfma_f32_16x16x32_bf16(a1, b3, acc[1][3], 0, 0, 0);
        accd[0]   = __builtin_amdgcn_mfma_f32_16x16x32_bf16(a0, vones, accd[0], 0, 0, 0);
        accd[1]   = __builtin_amdgcn_mfma_f32_16x16x32_bf16(a1, vones, accd[1], 0, 0, 0);
    }

    // ---- write this wave's partials (slot je); C/D layout: col=rit, row=q*4+rg
    #pragma unroll
    for (int rt = 0; rt < 2; ++rt)
        #pragma unroll
        for (int ct = 0; ct < 4; ++ct)
            #pragma unroll
            for (int rg = 0; rg < 4; ++rg)
                red[(size_t)je * (64 * 68) + (rgrp * 32 + rt * 16 + q * 4 + rg) * 68 + ct * 16 + rit]
                    = acc[rt][ct][rg];
    if (rit == 0) {
        #pragma unroll
        for (int rt = 0; rt < 2; ++rt)
            #pragma unroll
            for (int rg = 0; rg < 4; ++rg)
                dred[je * 64 + rgrp * 32 + rt * 16 + q * 4 + rg] = accd[rt][rg];
    }
    __syncthreads();

    // ---- block-wide combine + softmax divide + residual + layernorm
    const int row = t >> 4, cg = t & 15;
    float dsum = 0.f;
    #pragma unroll
    for (int sl = 0; sl < 8; ++sl) dsum += dred[sl * 64 + row];
    const float inv = 1.0f / dsum;
    const size_t rowg = (size_t)(b * 4096 + i0 + row);
    const float* xr = x + rowg * 64;

    float h[4], sm = 0.f, ss = 0.f;
    #pragma unroll
    for (int ct = 0; ct < 4; ++ct) {
        float num = 0.f;
        #pragma unroll
        for (int sl = 0; sl < 8; ++sl)
            num += red[(size_t)sl * (64 * 68) + row * 68 + ct * 16 + cg];
        h[ct] = num * inv + xr[ct * 16 + cg];
        sm += h[ct]; ss += h[ct] * h[ct];
    }
    #pragma unroll
    for (int m = 1; m < 16; m <<= 1) { sm += __shfl_xor(sm, m); ss += __shfl_xor(ss, m); }
    const float mu   = sm * 0.015625f;
    const float var  = ss * 0.015625f - mu * mu;
    const float rstd = rsqrtf(var + 1e-5f);

    float* orow = out + rowg * 64;
    #pragma unroll
    for (int ct = 0; ct < 4; ++ct)
        orow[ct * 16 + cg] = (h[ct] - mu) * rstd * gamma[ct * 16 + cg] + beta[ct * 16 + cg];
}

// ---------------------------------------------------------------------------
extern "C" void kernel_launch(void* const* d_in, const int* in_sizes, int n_in,
                              void* d_out, int out_size, void* d_ws, size_t ws_size,
                              hipStream_t stream)
{
    const float* x     = (const float*)d_in[0];
    const float* Wv    = (const float*)d_in[1];
    const float* bv    = (const float*)d_in[2];
    const float* wq    = (const float*)d_in[3];
    const float* wk    = (const float*)d_in[4];
    const float* gamma = (const float*)d_in[5];
    const float* beta  = (const float*)d_in[6];
    float* out = (float*)d_out;

    // workspace: Qs[16384] f32 | Ks[16384] f32 | Vt[4*64*4096] bf16  (~2.23 MB)
    float* Qs = (float*)d_ws;
    float* Ks = Qs + NTOK;
    unsigned short* Vt = (unsigned short*)(Ks + NTOK);

    // dynamic LDS: k 16384 B + red 8*64*68*4 = 139264 B + dred 2048 B
    const int attn_lds = 4096 * 4 + 8 * 64 * 68 * 4 + 8 * 64 * 4;
    static bool attr_set = false;   // idempotent host-side attr (not a stream op)
    hipFuncSetAttribute((const void*)attn_kernel,
                        hipFuncAttributeMaxDynamicSharedMemorySize, attn_lds);

    qkv_kernel<<<dim3(NTOK / 64), dim3(512), 0, stream>>>(x, Wv, bv, wq, wk, Qs, Ks, Vt);
    attn_kernel<<<dim3(NB * (NSEQ / 64)), dim3(1024), attn_lds, stream>>>(
        x, Qs, Ks, Vt, gamma, beta, out);
    (void)attr_set;
}